// Round 15
// baseline (3463.395 us; speedup 1.0000x reference)
//
#include <hip/hip_runtime.h>
#include <hip/hip_fp16.h>
#include <stdint.h>

#define Kn 64
#define En 256
#define Bn 512
#define Hn 512
#define Dn 128
#define NBLK 128     // 16 pairs x 8 slices; each block serves 2 groups (A,B)
#define NTH  256
#define DT_C 0.05f

// ws layout (bytes):
//   0        pos   int[Kn*Bn]           (128 KB)
//   131072   acc   float[2]
//   196608   flg   int[32*8*32]         (32 KB: [group][slice], 128B stride)
//   1048576  Hf    __half[512][512]     Euler h mirror
//   1572864  Tf    __half[512][512]     Euler tanh mirror
//   2097152  T2f   __half[512][512]     P1 relu mirror (deferred P2)
//   2621440  Hf2   __half[512][512]     LSTM h' mirror (obs rows)
//   4194304  WF    frag-swizzled f16 weights (4.33 MB)
// WF half-offsets: W1 0, W2 262144, Wp1 524288, Wp2 786432, Wg 851968
//   frag layout: idx = ((coltile*KT + ktile)*64 + lane)*8 + e
//   element = W[ktile*32 + (lane>>4)*8 + e][coltile*16 + (lane&15)]

typedef _Float16 f16x8 __attribute__((ext_vector_type(8)));
typedef float    f32x4 __attribute__((ext_vector_type(4)));
typedef unsigned long long u64;

__device__ __forceinline__ float sigm(float x){ return 1.0f/(1.0f + __expf(-x)); }

__device__ __forceinline__ u64 ald(const u64* p){
  return __hip_atomic_load(p, __ATOMIC_RELAXED, __HIP_MEMORY_SCOPE_AGENT);
}
__device__ __forceinline__ void ast(u64* p, u64 v){
  __hip_atomic_store(p, v, __ATOMIC_RELAXED, __HIP_MEMORY_SCOPE_AGENT);
}

union HU { __half h[8]; u64 q[2]; };

__global__ void k_init(int* __restrict__ pos, float* __restrict__ acc,
                       int* __restrict__ flg, uint32_t* __restrict__ hf){
  int i = blockIdx.x*blockDim.x + threadIdx.x;
  if (i < Kn*Bn) pos[i] = -1;
  if (i < 2) acc[i] = 0.0f;
  if (i < 32*8*32) flg[i] = 0;
  if (i < Hn*Hn/2) hf[i] = 0;
}

__global__ void k_scatter(const int* __restrict__ bidx, int* __restrict__ pos){
  int i = blockIdx.x*blockDim.x + threadIdx.x;
  if (i < Kn*En){
    int k = i >> 8;
    int e = i & (En-1);
    pos[(k << 9) | bidx[i]] = e;
  }
}

__global__ void k_cvt_frag(const float* __restrict__ src, __half* __restrict__ dst,
                           int KT, int N, int n){
  int i = blockIdx.x*blockDim.x + threadIdx.x;
  if (i >= n) return;
  int C = i / (KT*512);
  int r = i % (KT*512);
  int T = r >> 9;
  int q = r & 511;
  int l = q >> 3, e = q & 7;
  int srow = T*32 + ((l>>4)<<3) + e;
  int scol = C*16 + (l&15);
  dst[i] = __float2half(src[(size_t)srow*N + scol]);
}

__device__ __forceinline__ f32x4 mv16(const __half* Af, const f16x8* Wr, int lane){
  f32x4 a = {0.f,0.f,0.f,0.f};
  #pragma unroll
  for (int kt=0; kt<16; kt++){
    f16x8 av = *(const f16x8*)(Af + kt*512 + lane*8);
    a = __builtin_amdgcn_mfma_f32_16x16x32_f16(av, Wr[kt], a, 0,0,0);
  }
  return a;
}

__global__ __launch_bounds__(NTH, 1) void k_main(
  const float* __restrict__ X, const float* __restrict__ Mm,
  const int* __restrict__ pos, const __half* __restrict__ WF,
  __half* __restrict__ Hf, __half* __restrict__ Tf,
  __half* __restrict__ T2f, __half* __restrict__ Hf2,
  const float* __restrict__ bi_, const float* __restrict__ bf_,
  const float* __restrict__ bo_, const float* __restrict__ bc_,
  const float* __restrict__ b1_, const float* __restrict__ b2_,
  const float* __restrict__ bp1_, const float* __restrict__ bp2_,
  float* __restrict__ acc, int* __restrict__ flg)
{
  const __half* W1F  = WF;
  const __half* W2F  = WF + 262144;
  const __half* Wp1F = WF + 524288;
  const __half* Wp2F = WF + 786432;
  const __half* WgF  = WF + 851968;

  const int t    = threadIdx.x;
  const int bid  = blockIdx.x;
  const int s    = bid & 7;      // slice = XCD under round-robin (perf-only)
  const int qp   = bid >> 3;     // pair 0..15 -> groups 2qp, 2qp+1
  const int w    = t >> 6;
  const int lane = t & 63;

  __shared__ __align__(16) __half Afrag[16*512];   // 16KB (time-shared A/B)
  __shared__ __align__(16) __half Bfrag[16*512];   // 16KB (T2f staging)
  __shared__ __align__(16) __half Xfrag[4*512];    // 4KB
  __shared__ __align__(16) float  outb[20*256];    // 20KB
  __shared__ float redbuf[8];

  const int row = t >> 4;
  const int q4  = t & 15;
  const int sc  = s*64 + q4*4;
  float Hreg[2][4] = {{0,0,0,0},{0,0,0,0}};
  float Creg[2][4] = {{0,0,0,0},{0,0,0,0}};
  float vb1[4], vb2[4], vbp1[4], vbi[4], vbf[4], vbo[4], vbc[4];
  #pragma unroll
  for (int i=0;i<4;i++){
    vb1[i]=b1_[sc+i]; vb2[i]=b2_[sc+i]; vbp1[i]=bp1_[sc+i];
    vbi[i]=bi_[sc+i]; vbf[i]=bf_[sc+i]; vbo[i]=bo_[sc+i]; vbc[i]=bc_[sc+i];
  }
  const float vbp2 = bp2_[s*16 + q4];

  // hoisted weights shared across both chains
  f16x8 W1r[16], W2r[16], Wp1r[16];
  {
    const size_t cb = (size_t)(s*4 + w)*16*512 + (size_t)lane*8;
    #pragma unroll
    for (int kt=0; kt<16; kt++){
      W1r[kt]  = *(const f16x8*)(W1F  + cb + kt*512);
      W2r[kt]  = *(const f16x8*)(W2F  + cb + kt*512);
      Wp1r[kt] = *(const f16x8*)(Wp1F + cb + kt*512);
    }
  }

  float loss_loc = 0.f, m_loc = 0.f;
  int rnd = 0;

#define POLLF(FB, R) do{                                                   \
    if (t < 8){                                                            \
      while (__hip_atomic_load((FB) + t*32, __ATOMIC_RELAXED,              \
                               __HIP_MEMORY_SCOPE_AGENT) < (R))            \
        __builtin_amdgcn_s_sleep(1);                                       \
    }                                                                      \
    __syncthreads();                                                       \
  }while(0)

#define PUBF(FB, R) do{                                                    \
    asm volatile("s_waitcnt vmcnt(0)" ::: "memory");                       \
    __syncthreads();                                                       \
    if (t == 0)                                                            \
      __hip_atomic_store((FB) + s*32, (R), __ATOMIC_RELAXED,               \
                         __HIP_MEMORY_SCOPE_AGENT);                        \
  }while(0)

#define STAGE(DST, SRCPTR, G) do{                                          \
    const int ar = t & 15, ch = t >> 4;                                    \
    const u64* sp = (const u64*)((SRCPTR) + ((size_t)((G)*16+ar))*512 + ch*32); \
    u64 v[8];                                                              \
    _Pragma("unroll") for (int i=0;i<8;i++) v[i] = ald(sp+i);              \
    _Pragma("unroll")                                                      \
    for (int kg=0;kg<4;kg++){                                              \
      u64* d = (u64*)((DST) + ch*512 + (ar + 16*kg)*8);                    \
      d[0] = v[2*kg]; d[1] = v[2*kg+1];                                    \
    }                                                                      \
  }while(0)

  for (int k=0; k<Kn; k++){
    // ============ P1e (x2 chains): deferred P2+loss(k-1) + Euler s1-W1 ============
    #pragma unroll
    for (int c=0;c<2;c++){
      const int g = qp*2 + c;
      int* fb = flg + g*8*32;
      const int grow = g*16 + row;
      POLLF(fb, rnd);
      if (k > 0) STAGE(Bfrag, T2f, g);
      {
        const int ar = t & 15, ch = t >> 4;
        const __half* hsrc = Hf;
        if (k > 0 && pos[((k-1)<<9) + g*16 + ar] >= 0) hsrc = Hf2;
        const u64* sp = (const u64*)(hsrc + ((size_t)(g*16+ar))*512 + ch*32);
        u64 v[8];
        #pragma unroll
        for (int i=0;i<8;i++) v[i] = ald(sp+i);
        #pragma unroll
        for (int kg=0;kg<4;kg++){
          u64* d = (u64*)(Afrag + ch*512 + (ar + 16*kg)*8);
          d[0] = v[2*kg]; d[1] = v[2*kg+1];
        }
      }
      __syncthreads();
      {
        f32x4 a4 = mv16(Afrag, W1r, lane);
        float* o = outb + w*256 + ((lane>>4)*4)*16 + (lane&15);
        o[0]=a4[0]; o[16]=a4[1]; o[32]=a4[2]; o[48]=a4[3];
      }
      if (k > 0){
        const __half* wb = Wp2F + (size_t)s*16*512;
        f32x4 a4 = {0,0,0,0};
        #pragma unroll
        for (int kt2=0; kt2<4; kt2++){
          const int kt = w*4 + kt2;
          f16x8 a = *(const f16x8*)(Bfrag + kt*512 + lane*8);
          f16x8 b = *(const f16x8*)(wb + kt*512 + lane*8);
          a4 = __builtin_amdgcn_mfma_f32_16x16x32_f16(a, b, a4, 0,0,0);
        }
        float* o = outb + (16+w)*256 + ((lane>>4)*4)*16 + (lane&15);
        o[0]=a4[0]; o[16]=a4[1]; o[32]=a4[2]; o[48]=a4[3];
      }
      __syncthreads();
      {
        const float* o = outb + (q4>>2)*256 + row*16 + (q4&3)*4;
        HU u;
        u.h[0]=__float2half(tanhf(o[0]+vb1[0])); u.h[1]=__float2half(tanhf(o[1]+vb1[1]));
        u.h[2]=__float2half(tanhf(o[2]+vb1[2])); u.h[3]=__float2half(tanhf(o[3]+vb1[3]));
        ast((u64*)(Tf + (size_t)grow*512 + sc), u.q[0]);
      }
      PUBF(fb, rnd+1);
      if (k > 0){
        const int ep = pos[((k-1)<<9) + g*16 + row];
        if (ep >= 0){
          float p = outb[16*256 + row*16+q4] + outb[17*256 + row*16+q4]
                  + outb[18*256 + row*16+q4] + outb[19*256 + row*16+q4] + vbp2;
          const size_t xo = ((size_t)((k-1)*En+ep))*Dn + s*16 + q4;
          float mo = Mm[xo];
          loss_loc += fabsf(X[xo] - p)*mo;
          m_loc    += mo;
        }
      }
    }
    rnd++;

    // ============ P2e (x2): Euler s1-W2, h += dt(..) ============
    #pragma unroll
    for (int c=0;c<2;c++){
      const int g = qp*2 + c;
      int* fb = flg + g*8*32;
      const int grow = g*16 + row;
      POLLF(fb, rnd);
      STAGE(Afrag, Tf, g);
      __syncthreads();
      {
        f32x4 a4 = mv16(Afrag, W2r, lane);
        float* o = outb + w*256 + ((lane>>4)*4)*16 + (lane&15);
        o[0]=a4[0]; o[16]=a4[1]; o[32]=a4[2]; o[48]=a4[3];
      }
      __syncthreads();
      {
        const float* o = outb + (q4>>2)*256 + row*16 + (q4&3)*4;
        HU u;
        Hreg[c][0] += DT_C*(o[0]+vb2[0]); Hreg[c][1] += DT_C*(o[1]+vb2[1]);
        Hreg[c][2] += DT_C*(o[2]+vb2[2]); Hreg[c][3] += DT_C*(o[3]+vb2[3]);
        u.h[0]=__float2half(Hreg[c][0]); u.h[1]=__float2half(Hreg[c][1]);
        u.h[2]=__float2half(Hreg[c][2]); u.h[3]=__float2half(Hreg[c][3]);
        ast((u64*)(Hf + (size_t)grow*512 + sc), u.q[0]);
      }
      PUBF(fb, rnd+1);
    }
    rnd++;

    // ============ P3e (x2): Euler s2-W1 ============
    #pragma unroll
    for (int c=0;c<2;c++){
      const int g = qp*2 + c;
      int* fb = flg + g*8*32;
      const int grow = g*16 + row;
      POLLF(fb, rnd);
      STAGE(Afrag, Hf, g);
      __syncthreads();
      {
        f32x4 a4 = mv16(Afrag, W1r, lane);
        float* o = outb + w*256 + ((lane>>4)*4)*16 + (lane&15);
        o[0]=a4[0]; o[16]=a4[1]; o[32]=a4[2]; o[48]=a4[3];
      }
      __syncthreads();
      {
        const float* o = outb + (q4>>2)*256 + row*16 + (q4&3)*4;
        HU u;
        u.h[0]=__float2half(tanhf(o[0]+vb1[0])); u.h[1]=__float2half(tanhf(o[1]+vb1[1]));
        u.h[2]=__float2half(tanhf(o[2]+vb1[2])); u.h[3]=__float2half(tanhf(o[3]+vb1[3]));
        ast((u64*)(Tf + (size_t)grow*512 + sc), u.q[0]);
      }
      PUBF(fb, rnd+1);
    }
    rnd++;

    // ============ P4e (x2): Euler s2-W2 ============
    #pragma unroll
    for (int c=0;c<2;c++){
      const int g = qp*2 + c;
      int* fb = flg + g*8*32;
      const int grow = g*16 + row;
      POLLF(fb, rnd);
      STAGE(Afrag, Tf, g);
      __syncthreads();
      {
        f32x4 a4 = mv16(Afrag, W2r, lane);
        float* o = outb + w*256 + ((lane>>4)*4)*16 + (lane&15);
        o[0]=a4[0]; o[16]=a4[1]; o[32]=a4[2]; o[48]=a4[3];
      }
      __syncthreads();
      {
        const float* o = outb + (q4>>2)*256 + row*16 + (q4&3)*4;
        HU u;
        Hreg[c][0] += DT_C*(o[0]+vb2[0]); Hreg[c][1] += DT_C*(o[1]+vb2[1]);
        Hreg[c][2] += DT_C*(o[2]+vb2[2]); Hreg[c][3] += DT_C*(o[3]+vb2[3]);
        u.h[0]=__float2half(Hreg[c][0]); u.h[1]=__float2half(Hreg[c][1]);
        u.h[2]=__float2half(Hreg[c][2]); u.h[3]=__float2half(Hreg[c][3]);
        ast((u64*)(Hf + (size_t)grow*512 + sc), u.q[0]);
      }
      PUBF(fb, rnd+1);
    }
    rnd++;

    // ====== P56 (x2): P1 -> T2f, gates, LSTM -> Hf2 ======
    #pragma unroll
    for (int c=0;c<2;c++){
      const int g = qp*2 + c;
      int* fb = flg + g*8*32;
      const int grow = g*16 + row;
      const int epos = pos[(k<<9) + grow];
      POLLF(fb, rnd);
      STAGE(Afrag, Hf, g);
      if (t < 64){
        const int ar = t & 15, ch = t >> 4;
        const int e = pos[(k<<9) + g*16 + ar];
        float xv[32];
        if (e >= 0){
          const float4* xp = (const float4*)(X + ((size_t)(k*En+e))*Dn + ch*32);
          #pragma unroll
          for (int i=0;i<8;i++){
            float4 f = xp[i];
            xv[4*i]=f.x; xv[4*i+1]=f.y; xv[4*i+2]=f.z; xv[4*i+3]=f.w;
          }
        } else {
          #pragma unroll
          for (int i=0;i<32;i++) xv[i]=0.f;
        }
        #pragma unroll
        for (int kg=0;kg<4;kg++){
          HU u;
          #pragma unroll
          for (int e8=0;e8<8;e8++) u.h[e8] = __float2half(xv[kg*8+e8]);
          u64* d = (u64*)(Xfrag + ch*512 + (ar + 16*kg)*8);
          d[0] = u.q[0]; d[1] = u.q[1];
        }
      }
      __syncthreads();
      {
        f32x4 a4 = mv16(Afrag, Wp1r, lane);
        float* o = outb + (16+w)*256 + ((lane>>4)*4)*16 + (lane&15);
        o[0]=a4[0]; o[16]=a4[1]; o[32]=a4[2]; o[48]=a4[3];
      }
      #pragma unroll 1
      for (int i=0;i<4;i++){
        const int Cg = w*32 + s*4 + i;
        const __half* wb = WgF + (size_t)Cg*20*512;
        f32x4 a4 = {0,0,0,0};
        #pragma unroll 4
        for (int kt=0; kt<4; kt++){
          f16x8 a = *(const f16x8*)(Xfrag + kt*512 + lane*8);
          f16x8 b = *(const f16x8*)(wb + kt*512 + lane*8);
          a4 = __builtin_amdgcn_mfma_f32_16x16x32_f16(a, b, a4, 0,0,0);
        }
        #pragma unroll 4
        for (int kt=4; kt<20; kt++){
          f16x8 a = *(const f16x8*)(Afrag + (kt-4)*512 + lane*8);
          f16x8 b = *(const f16x8*)(wb + kt*512 + lane*8);
          a4 = __builtin_amdgcn_mfma_f32_16x16x32_f16(a, b, a4, 0,0,0);
        }
        float* o = outb + (w*4+i)*256 + ((lane>>4)*4)*16 + (lane&15);
        o[0]=a4[0]; o[16]=a4[1]; o[32]=a4[2]; o[48]=a4[3];
      }
      __syncthreads();
      {
        const float* o = outb + (16+(q4>>2))*256 + row*16 + (q4&3)*4;
        HU u;
        u.h[0]=__float2half(fmaxf(o[0]+vbp1[0],0.f));
        u.h[1]=__float2half(fmaxf(o[1]+vbp1[1],0.f));
        u.h[2]=__float2half(fmaxf(o[2]+vbp1[2],0.f));
        u.h[3]=__float2half(fmaxf(o[3]+vbp1[3],0.f));
        ast((u64*)(T2f + (size_t)grow*512 + sc), u.q[0]);
      }
      if (epos >= 0){
        const int sub = q4 >> 2, off = row*16 + (q4&3)*4;
        const float4 pi = *(const float4*)(outb + (0*4+sub)*256 + off);
        const float4 pf = *(const float4*)(outb + (1*4+sub)*256 + off);
        const float4 po = *(const float4*)(outb + (2*4+sub)*256 + off);
        const float4 pc = *(const float4*)(outb + (3*4+sub)*256 + off);
        HU hu;
        const float gi[4]={pi.x,pi.y,pi.z,pi.w}, gf[4]={pf.x,pf.y,pf.z,pf.w};
        const float go[4]={po.x,po.y,po.z,po.w}, gc[4]={pc.x,pc.y,pc.z,pc.w};
        #pragma unroll
        for (int i=0;i<4;i++){
          float ig = sigm(gi[i] + vbi[i]);
          float fg = sigm(gf[i] + vbf[i]);
          float og = sigm(go[i] + vbo[i]);
          float ct = tanhf(gc[i] + vbc[i]);
          Creg[c][i] = fg*Creg[c][i] + ig*ct;
          Hreg[c][i] = og*tanhf(Creg[c][i]);
          hu.h[i] = __float2half(Hreg[c][i]);
        }
        ast((u64*)(Hf2 + (size_t)grow*512 + sc), hu.q[0]);
      }
      PUBF(fb, rnd+1);
    }
    rnd++;
  }

  // ===== epilogue (x2): deferred P2+loss for event Kn-1 =====
  #pragma unroll
  for (int c=0;c<2;c++){
    const int g = qp*2 + c;
    int* fb = flg + g*8*32;
    POLLF(fb, rnd);
    STAGE(Bfrag, T2f, g);
    __syncthreads();
    {
      const __half* wb = Wp2F + (size_t)s*16*512;
      f32x4 a4 = {0,0,0,0};
      #pragma unroll
      for (int kt2=0; kt2<4; kt2++){
        const int kt = w*4 + kt2;
        f16x8 a = *(const f16x8*)(Bfrag + kt*512 + lane*8);
        f16x8 b = *(const f16x8*)(wb + kt*512 + lane*8);
        a4 = __builtin_amdgcn_mfma_f32_16x16x32_f16(a, b, a4, 0,0,0);
      }
      float* o = outb + (16+w)*256 + ((lane>>4)*4)*16 + (lane&15);
      o[0]=a4[0]; o[16]=a4[1]; o[32]=a4[2]; o[48]=a4[3];
    }
    __syncthreads();
    {
      const int ep = pos[((Kn-1)<<9) + g*16 + row];
      if (ep >= 0){
        float p = outb[16*256 + row*16+q4] + outb[17*256 + row*16+q4]
                + outb[18*256 + row*16+q4] + outb[19*256 + row*16+q4] + vbp2;
        const size_t xo = ((size_t)((Kn-1)*En+ep))*Dn + s*16 + q4;
        float mo = Mm[xo];
        loss_loc += fabsf(X[xo] - p)*mo;
        m_loc    += mo;
      }
    }
    __syncthreads();
  }

  // block reduction -> global atomics
  #pragma unroll
  for (int off=32; off>0; off>>=1){
    loss_loc += __shfl_down(loss_loc, off);
    m_loc    += __shfl_down(m_loc, off);
  }
  if (lane == 0){ redbuf[w] = loss_loc; redbuf[4+w] = m_loc; }
  __syncthreads();
  if (t == 0){
    atomicAdd(acc+0, redbuf[0]+redbuf[1]+redbuf[2]+redbuf[3]);
    atomicAdd(acc+1, redbuf[4]+redbuf[5]+redbuf[6]+redbuf[7]);
  }
#undef POLLF
#undef PUBF
#undef STAGE
}

__global__ void k_fin(const float* __restrict__ acc, float* __restrict__ out){
  if (threadIdx.x == 0){
    out[0] = acc[0];
    out[1] = acc[0]/acc[1];
  }
}

extern "C" void kernel_launch(void* const* d_in, const int* in_sizes, int n_in,
                              void* d_out, int out_size, void* d_ws, size_t ws_size,
                              hipStream_t stream)
{
  const float* X   = (const float*)d_in[0];
  const float* Mm  = (const float*)d_in[1];
  const int*  bidx = (const int*)d_in[2];
  // d_in[3] = sample_idx (arange, unused)
  const float* Wi  = (const float*)d_in[4];
  const float* bi  = (const float*)d_in[5];
  const float* Wf  = (const float*)d_in[6];
  const float* bff = (const float*)d_in[7];
  const float* Wo  = (const float*)d_in[8];
  const float* bo  = (const float*)d_in[9];
  const float* Wc  = (const float*)d_in[10];
  const float* bc  = (const float*)d_in[11];
  const float* W1  = (const float*)d_in[12];
  const float* b1  = (const float*)d_in[13];
  const float* W2  = (const float*)d_in[14];
  const float* b2  = (const float*)d_in[15];
  const float* Wp1 = (const float*)d_in[16];
  const float* bp1 = (const float*)d_in[17];
  const float* Wp2 = (const float*)d_in[18];
  const float* bp2 = (const float*)d_in[19];

  char* ws = (char*)d_ws;
  int*    pos = (int*)ws;
  float*  acc = (float*)(ws + 131072);
  int*    flg = (int*)(ws + 196608);
  __half* Hf  = (__half*)(ws + 1048576);
  __half* Tf  = (__half*)(ws + 1572864);
  __half* T2f = (__half*)(ws + 2097152);
  __half* Hf2 = (__half*)(ws + 2621440);
  __half* WF  = (__half*)(ws + 4194304);

  k_init   <<<512, 256, 0, stream>>>(pos, acc, flg, (uint32_t*)Hf);
  k_scatter<<<(Kn*En + 255)/256, 256, 0, stream>>>(bidx, pos);

  k_cvt_frag<<<(262144+255)/256, 256, 0, stream>>>(W1,  WF,          16, 512, 262144);
  k_cvt_frag<<<(262144+255)/256, 256, 0, stream>>>(W2,  WF + 262144, 16, 512, 262144);
  k_cvt_frag<<<(262144+255)/256, 256, 0, stream>>>(Wp1, WF + 524288, 16, 512, 262144);
  k_cvt_frag<<<(65536 +255)/256, 256, 0, stream>>>(Wp2, WF + 786432, 16, 128, 65536);
  k_cvt_frag<<<(327680+255)/256, 256, 0, stream>>>(Wi,  WF + 851968,            20, 512, 327680);
  k_cvt_frag<<<(327680+255)/256, 256, 0, stream>>>(Wf,  WF + 851968 + 327680,   20, 512, 327680);
  k_cvt_frag<<<(327680+255)/256, 256, 0, stream>>>(Wo,  WF + 851968 + 655360,   20, 512, 327680);
  k_cvt_frag<<<(327680+255)/256, 256, 0, stream>>>(Wc,  WF + 851968 + 983040,   20, 512, 327680);

  k_main<<<NBLK, NTH, 0, stream>>>(X, Mm, pos, WF, Hf, Tf, T2f, Hf2,
                                   bi, bff, bo, bc, b1, b2, bp1, bp2, acc, flg);
  k_fin<<<1, 64, 0, stream>>>(acc, (float*)d_out);
}

// Round 16
// 1888.940 us; speedup vs baseline: 1.8335x; 1.8335x over previous
//
#include <hip/hip_runtime.h>
#include <hip/hip_fp16.h>
#include <stdint.h>

#define Kn 64
#define En 256
#define Bn 512
#define Hn 512
#define Dn 128
#define NBLK 256
#define NTH  256
#define DT_C 0.05f

// ws layout (bytes):
//   0        pos   int[Kn*Bn]           (128 KB)
//   131072   acc   float[2]
//   196608   flg   int[32*8*32]         (32 KB: [group][slice], 128B stride)
//   1048576  Hf    __half[512][512]     Euler h mirror
//   1572864  Tf    __half[512][512]     Euler tanh mirror
//   2097152  T2f   __half[512][512]     P1 relu mirror (deferred P2)
//   2621440  Hf2   __half[512][512]     LSTM h' mirror (obs rows)
//   4194304  WF    frag-swizzled f16 weights (4.33 MB)
// WF half-offsets: W1 0, W2 262144, Wp1 524288, Wp2 786432, Wg 851968
//   frag layout: idx = ((coltile*KT + ktile)*64 + lane)*8 + e
//   element = W[ktile*32 + (lane>>4)*8 + e][coltile*16 + (lane&15)]

typedef _Float16 f16x8 __attribute__((ext_vector_type(8)));
typedef float    f32x4 __attribute__((ext_vector_type(4)));
typedef unsigned long long u64;

__device__ __forceinline__ float sigm(float x){ return 1.0f/(1.0f + __expf(-x)); }

__device__ __forceinline__ u64 ald(const u64* p){
  return __hip_atomic_load(p, __ATOMIC_RELAXED, __HIP_MEMORY_SCOPE_AGENT);
}
__device__ __forceinline__ void ast(u64* p, u64 v){
  __hip_atomic_store(p, v, __ATOMIC_RELAXED, __HIP_MEMORY_SCOPE_AGENT);
}

union HU { __half h[8]; u64 q[2]; };

__global__ void k_init(int* __restrict__ pos, float* __restrict__ acc,
                       int* __restrict__ flg, uint32_t* __restrict__ hf){
  int i = blockIdx.x*blockDim.x + threadIdx.x;
  if (i < Kn*Bn) pos[i] = -1;
  if (i < 2) acc[i] = 0.0f;
  if (i < 32*8*32) flg[i] = 0;
  if (i < Hn*Hn/2) hf[i] = 0;
}

__global__ void k_scatter(const int* __restrict__ bidx, int* __restrict__ pos){
  int i = blockIdx.x*blockDim.x + threadIdx.x;
  if (i < Kn*En){
    int k = i >> 8;
    int e = i & (En-1);
    pos[(k << 9) | bidx[i]] = e;
  }
}

__global__ void k_cvt_frag(const float* __restrict__ src, __half* __restrict__ dst,
                           int KT, int N, int n){
  int i = blockIdx.x*blockDim.x + threadIdx.x;
  if (i >= n) return;
  int C = i / (KT*512);
  int r = i % (KT*512);
  int T = r >> 9;
  int q = r & 511;
  int l = q >> 3, e = q & 7;
  int srow = T*32 + ((l>>4)<<3) + e;
  int scol = C*16 + (l&15);
  dst[i] = __float2half(src[(size_t)srow*N + scol]);
}

__device__ __forceinline__ f32x4 mv16(const __half* Af, const f16x8* Wr, int lane){
  f32x4 a = {0.f,0.f,0.f,0.f};
  #pragma unroll
  for (int kt=0; kt<16; kt++){
    f16x8 av = *(const f16x8*)(Af + kt*512 + lane*8);
    a = __builtin_amdgcn_mfma_f32_16x16x32_f16(av, Wr[kt], a, 0,0,0);
  }
  return a;
}

__global__ __launch_bounds__(NTH, 1) void k_main(
  const float* __restrict__ X, const float* __restrict__ Mm,
  const int* __restrict__ pos, const __half* __restrict__ WF,
  __half* __restrict__ Hf, __half* __restrict__ Tf,
  __half* __restrict__ T2f, __half* __restrict__ Hf2,
  const float* __restrict__ bi_, const float* __restrict__ bf_,
  const float* __restrict__ bo_, const float* __restrict__ bc_,
  const float* __restrict__ b1_, const float* __restrict__ b2_,
  const float* __restrict__ bp1_, const float* __restrict__ bp2_,
  float* __restrict__ acc, int* __restrict__ flg)
{
  const __half* W1F  = WF;
  const __half* W2F  = WF + 262144;
  const __half* Wp1F = WF + 524288;
  const __half* Wp2F = WF + 786432;
  const __half* WgF  = WF + 851968;

  const int t    = threadIdx.x;
  const int bid  = blockIdx.x;
  const int s    = bid & 7;      // slice = XCD under round-robin (perf-only)
  const int g    = bid >> 3;     // group 0..31
  const int w    = t >> 6;
  const int lane = t & 63;
  int* flgbase = flg + g*8*32;

  __shared__ __align__(16) __half Afrag[16*512];   // 16KB
  __shared__ __align__(16) __half Bfrag[16*512];   // 16KB (deferred T2f staging)
  __shared__ __align__(16) __half Xfrag[4*512];    // 4KB
  __shared__ __align__(16) float  outb[20*256];    // 20KB
  __shared__ float redbuf[8];

  const int row = t >> 4;
  const int q4  = t & 15;
  const int sc  = s*64 + q4*4;
  float Hreg[4] = {0,0,0,0};
  float Creg[4] = {0,0,0,0};
  float vb1[4], vb2[4], vbp1[4], vbi[4], vbf[4], vbo[4], vbc[4];
  #pragma unroll
  for (int i=0;i<4;i++){
    vb1[i]=b1_[sc+i]; vb2[i]=b2_[sc+i]; vbp1[i]=bp1_[sc+i];
    vbi[i]=bi_[sc+i]; vbf[i]=bf_[sc+i]; vbo[i]=bo_[sc+i]; vbc[i]=bc_[sc+i];
  }
  const float vbp2 = bp2_[s*16 + q4];

  // hoist W1/W2/Wp1 wave-slices into registers (R7-proven)
  f16x8 W1r[16], W2r[16], Wp1r[16];
  {
    const size_t cb = (size_t)(s*4 + w)*16*512 + (size_t)lane*8;
    #pragma unroll
    for (int kt=0; kt<16; kt++){
      W1r[kt]  = *(const f16x8*)(W1F  + cb + kt*512);
      W2r[kt]  = *(const f16x8*)(W2F  + cb + kt*512);
      Wp1r[kt] = *(const f16x8*)(Wp1F + cb + kt*512);
    }
  }

  float loss_loc = 0.f, m_loc = 0.f;
  int rnd = 0;
  const int grow = g*16 + row;

#define POLL() do{                                                         \
    if (t < 8){                                                            \
      while (__hip_atomic_load(flgbase + t*32, __ATOMIC_RELAXED,           \
                               __HIP_MEMORY_SCOPE_AGENT) < rnd)            \
        __builtin_amdgcn_s_sleep(1);                                       \
    }                                                                      \
    __syncthreads();                                                       \
  }while(0)

#define PUBLISH() do{                                                      \
    asm volatile("s_waitcnt vmcnt(0)" ::: "memory");                       \
    __syncthreads();                                                       \
    rnd++;                                                                 \
    if (t == 0)                                                            \
      __hip_atomic_store(flgbase + s*32, rnd, __ATOMIC_RELAXED,            \
                         __HIP_MEMORY_SCOPE_AGENT);                        \
  }while(0)

// stage 16 rows x 512 cols from SRC (u64 ald) into A-frag layout at DST
#define STAGE(DST, SRCPTR) do{                                             \
    const int ar = t & 15, ch = t >> 4;                                    \
    const u64* sp = (const u64*)((SRCPTR) + ((size_t)(g*16+ar))*512 + ch*32); \
    u64 v[8];                                                              \
    _Pragma("unroll") for (int i=0;i<8;i++) v[i] = ald(sp+i);              \
    _Pragma("unroll")                                                      \
    for (int kg=0;kg<4;kg++){                                              \
      u64* d = (u64*)((DST) + ch*512 + (ar + 16*kg)*8);                    \
      d[0] = v[2*kg]; d[1] = v[2*kg+1];                                    \
    }                                                                      \
  }while(0)

  for (int k=0; k<Kn; k++){
    const int epos = pos[(k<<9) + grow];

    // ============ P1e: deferred P2+loss (k-1) + Euler step1-W1 ============
    POLL();
    if (k > 0) STAGE(Bfrag, T2f);
    {
      // stage h with per-row select: obs(k-1) rows from Hf2, else Hf
      const int ar = t & 15, ch = t >> 4;
      const __half* hsrc = Hf;
      if (k > 0 && pos[((k-1)<<9) + g*16 + ar] >= 0) hsrc = Hf2;
      const u64* sp = (const u64*)(hsrc + ((size_t)(g*16+ar))*512 + ch*32);
      u64 v[8];
      #pragma unroll
      for (int i=0;i<8;i++) v[i] = ald(sp+i);
      #pragma unroll
      for (int kg=0;kg<4;kg++){
        u64* d = (u64*)(Afrag + ch*512 + (ar + 16*kg)*8);
        d[0] = v[2*kg]; d[1] = v[2*kg+1];
      }
    }
    __syncthreads();
    {
      f32x4 a4 = mv16(Afrag, W1r, lane);
      float* o = outb + w*256 + ((lane>>4)*4)*16 + (lane&15);
      o[0]=a4[0]; o[16]=a4[1]; o[32]=a4[2]; o[48]=a4[3];
    }
    if (k > 0){
      // deferred P2 for event k-1: coltile s of Wp2, wave w ktiles w*4..+3
      const __half* wb = Wp2F + (size_t)s*16*512;
      f32x4 a4 = {0,0,0,0};
      #pragma unroll
      for (int kt2=0; kt2<4; kt2++){
        const int kt = w*4 + kt2;
        f16x8 a = *(const f16x8*)(Bfrag + kt*512 + lane*8);
        f16x8 b = *(const f16x8*)(wb + kt*512 + lane*8);
        a4 = __builtin_amdgcn_mfma_f32_16x16x32_f16(a, b, a4, 0,0,0);
      }
      float* o = outb + (16+w)*256 + ((lane>>4)*4)*16 + (lane&15);
      o[0]=a4[0]; o[16]=a4[1]; o[32]=a4[2]; o[48]=a4[3];
    }
    __syncthreads();
    {
      const float* o = outb + (q4>>2)*256 + row*16 + (q4&3)*4;
      HU u;
      u.h[0]=__float2half(tanhf(o[0]+vb1[0])); u.h[1]=__float2half(tanhf(o[1]+vb1[1]));
      u.h[2]=__float2half(tanhf(o[2]+vb1[2])); u.h[3]=__float2half(tanhf(o[3]+vb1[3]));
      ast((u64*)(Tf + (size_t)grow*512 + sc), u.q[0]);
    }
    PUBLISH();
    if (k > 0){   // loss for event k-1 in barrier shadow (block-local)
      const int ep = pos[((k-1)<<9) + g*16 + row];
      if (ep >= 0){
        float p = outb[16*256 + row*16+q4] + outb[17*256 + row*16+q4]
                + outb[18*256 + row*16+q4] + outb[19*256 + row*16+q4] + vbp2;
        const size_t xo = ((size_t)((k-1)*En+ep))*Dn + s*16 + q4;
        float mo = Mm[xo];
        loss_loc += fabsf(X[xo] - p)*mo;
        m_loc    += mo;
      }
    }

    // ============ P2e: Euler step1-W2 (h += dt*(T@W2+b2)) ============
    POLL();
    STAGE(Afrag, Tf);
    __syncthreads();
    {
      f32x4 a4 = mv16(Afrag, W2r, lane);
      float* o = outb + w*256 + ((lane>>4)*4)*16 + (lane&15);
      o[0]=a4[0]; o[16]=a4[1]; o[32]=a4[2]; o[48]=a4[3];
    }
    __syncthreads();
    {
      const float* o = outb + (q4>>2)*256 + row*16 + (q4&3)*4;
      HU u;
      Hreg[0] += DT_C*(o[0]+vb2[0]); Hreg[1] += DT_C*(o[1]+vb2[1]);
      Hreg[2] += DT_C*(o[2]+vb2[2]); Hreg[3] += DT_C*(o[3]+vb2[3]);
      u.h[0]=__float2half(Hreg[0]); u.h[1]=__float2half(Hreg[1]);
      u.h[2]=__float2half(Hreg[2]); u.h[3]=__float2half(Hreg[3]);
      ast((u64*)(Hf + (size_t)grow*512 + sc), u.q[0]);
    }
    PUBLISH();

    // ============ P3e: Euler step2-W1 ============
    POLL();
    STAGE(Afrag, Hf);
    __syncthreads();
    {
      f32x4 a4 = mv16(Afrag, W1r, lane);
      float* o = outb + w*256 + ((lane>>4)*4)*16 + (lane&15);
      o[0]=a4[0]; o[16]=a4[1]; o[32]=a4[2]; o[48]=a4[3];
    }
    __syncthreads();
    {
      const float* o = outb + (q4>>2)*256 + row*16 + (q4&3)*4;
      HU u;
      u.h[0]=__float2half(tanhf(o[0]+vb1[0])); u.h[1]=__float2half(tanhf(o[1]+vb1[1]));
      u.h[2]=__float2half(tanhf(o[2]+vb1[2])); u.h[3]=__float2half(tanhf(o[3]+vb1[3]));
      ast((u64*)(Tf + (size_t)grow*512 + sc), u.q[0]);
    }
    PUBLISH();

    // ============ P4e: Euler step2-W2 ============
    POLL();
    STAGE(Afrag, Tf);
    __syncthreads();
    {
      f32x4 a4 = mv16(Afrag, W2r, lane);
      float* o = outb + w*256 + ((lane>>4)*4)*16 + (lane&15);
      o[0]=a4[0]; o[16]=a4[1]; o[32]=a4[2]; o[48]=a4[3];
    }
    __syncthreads();
    {
      const float* o = outb + (q4>>2)*256 + row*16 + (q4&3)*4;
      HU u;
      Hreg[0] += DT_C*(o[0]+vb2[0]); Hreg[1] += DT_C*(o[1]+vb2[1]);
      Hreg[2] += DT_C*(o[2]+vb2[2]); Hreg[3] += DT_C*(o[3]+vb2[3]);
      u.h[0]=__float2half(Hreg[0]); u.h[1]=__float2half(Hreg[1]);
      u.h[2]=__float2half(Hreg[2]); u.h[3]=__float2half(Hreg[3]);
      ast((u64*)(Hf + (size_t)grow*512 + sc), u.q[0]);
    }
    PUBLISH();

    // ====== P56: P1 -> T2f, gates, LSTM -> Hf2 (one barrier) ======
    POLL();
    STAGE(Afrag, Hf);
    if (t < 64){
      const int ar = t & 15, ch = t >> 4;
      const int e = pos[(k<<9) + g*16 + ar];
      float xv[32];
      if (e >= 0){
        const float4* xp = (const float4*)(X + ((size_t)(k*En+e))*Dn + ch*32);
        #pragma unroll
        for (int i=0;i<8;i++){
          float4 f = xp[i];
          xv[4*i]=f.x; xv[4*i+1]=f.y; xv[4*i+2]=f.z; xv[4*i+3]=f.w;
        }
      } else {
        #pragma unroll
        for (int i=0;i<32;i++) xv[i]=0.f;
      }
      #pragma unroll
      for (int kg=0;kg<4;kg++){
        HU u;
        #pragma unroll
        for (int e8=0;e8<8;e8++) u.h[e8] = __float2half(xv[kg*8+e8]);
        u64* d = (u64*)(Xfrag + ch*512 + (ar + 16*kg)*8);
        d[0] = u.q[0]; d[1] = u.q[1];
      }
    }
    __syncthreads();
    {   // P1 -> outb 16+w
      f32x4 a4 = mv16(Afrag, Wp1r, lane);
      float* o = outb + (16+w)*256 + ((lane>>4)*4)*16 + (lane&15);
      o[0]=a4[0]; o[16]=a4[1]; o[32]=a4[2]; o[48]=a4[3];
    }
    // gates: Cg = w*32 + s*4 + i -> outb slots w*4+i
    #pragma unroll 1
    for (int i=0;i<4;i++){
      const int Cg = w*32 + s*4 + i;
      const __half* wb = WgF + (size_t)Cg*20*512;
      f32x4 a4 = {0,0,0,0};
      #pragma unroll 4
      for (int kt=0; kt<4; kt++){
        f16x8 a = *(const f16x8*)(Xfrag + kt*512 + lane*8);
        f16x8 b = *(const f16x8*)(wb + kt*512 + lane*8);
        a4 = __builtin_amdgcn_mfma_f32_16x16x32_f16(a, b, a4, 0,0,0);
      }
      #pragma unroll 4
      for (int kt=4; kt<20; kt++){
        f16x8 a = *(const f16x8*)(Afrag + (kt-4)*512 + lane*8);
        f16x8 b = *(const f16x8*)(wb + kt*512 + lane*8);
        a4 = __builtin_amdgcn_mfma_f32_16x16x32_f16(a, b, a4, 0,0,0);
      }
      float* o = outb + (w*4+i)*256 + ((lane>>4)*4)*16 + (lane&15);
      o[0]=a4[0]; o[16]=a4[1]; o[32]=a4[2]; o[48]=a4[3];
    }
    __syncthreads();
    {   // relu(P1) -> T2f (read by deferred P2 next event)
      const float* o = outb + (16+(q4>>2))*256 + row*16 + (q4&3)*4;
      HU u;
      u.h[0]=__float2half(fmaxf(o[0]+vbp1[0],0.f));
      u.h[1]=__float2half(fmaxf(o[1]+vbp1[1],0.f));
      u.h[2]=__float2half(fmaxf(o[2]+vbp1[2],0.f));
      u.h[3]=__float2half(fmaxf(o[3]+vbp1[3],0.f));
      ast((u64*)(T2f + (size_t)grow*512 + sc), u.q[0]);
    }
    if (epos >= 0){   // LSTM update -> Hf2 (obs rows only; Hreg/Creg canonical)
      const int sub = q4 >> 2, off = row*16 + (q4&3)*4;
      const float4 pi = *(const float4*)(outb + (0*4+sub)*256 + off);
      const float4 pf = *(const float4*)(outb + (1*4+sub)*256 + off);
      const float4 po = *(const float4*)(outb + (2*4+sub)*256 + off);
      const float4 pc = *(const float4*)(outb + (3*4+sub)*256 + off);
      HU hu;
      const float gi[4]={pi.x,pi.y,pi.z,pi.w}, gf[4]={pf.x,pf.y,pf.z,pf.w};
      const float go[4]={po.x,po.y,po.z,po.w}, gc[4]={pc.x,pc.y,pc.z,pc.w};
      #pragma unroll
      for (int i=0;i<4;i++){
        float ig = sigm(gi[i] + vbi[i]);
        float fg = sigm(gf[i] + vbf[i]);
        float og = sigm(go[i] + vbo[i]);
        float ct = tanhf(gc[i] + vbc[i]);
        Creg[i] = fg*Creg[i] + ig*ct;
        Hreg[i] = og*tanhf(Creg[i]);
        hu.h[i] = __float2half(Hreg[i]);
      }
      ast((u64*)(Hf2 + (size_t)grow*512 + sc), hu.q[0]);
    }
    PUBLISH();
  }

  // ===== epilogue: deferred P2+loss for event Kn-1 =====
  POLL();
  STAGE(Bfrag, T2f);
  __syncthreads();
  {
    const __half* wb = Wp2F + (size_t)s*16*512;
    f32x4 a4 = {0,0,0,0};
    #pragma unroll
    for (int kt2=0; kt2<4; kt2++){
      const int kt = w*4 + kt2;
      f16x8 a = *(const f16x8*)(Bfrag + kt*512 + lane*8);
      f16x8 b = *(const f16x8*)(wb + kt*512 + lane*8);
      a4 = __builtin_amdgcn_mfma_f32_16x16x32_f16(a, b, a4, 0,0,0);
    }
    float* o = outb + (16+w)*256 + ((lane>>4)*4)*16 + (lane&15);
    o[0]=a4[0]; o[16]=a4[1]; o[32]=a4[2]; o[48]=a4[3];
  }
  __syncthreads();
  {
    const int ep = pos[((Kn-1)<<9) + g*16 + row];
    if (ep >= 0){
      float p = outb[16*256 + row*16+q4] + outb[17*256 + row*16+q4]
              + outb[18*256 + row*16+q4] + outb[19*256 + row*16+q4] + vbp2;
      const size_t xo = ((size_t)((Kn-1)*En+ep))*Dn + s*16 + q4;
      float mo = Mm[xo];
      loss_loc += fabsf(X[xo] - p)*mo;
      m_loc    += mo;
    }
  }

  // block reduction -> global atomics
  #pragma unroll
  for (int off=32; off>0; off>>=1){
    loss_loc += __shfl_down(loss_loc, off);
    m_loc    += __shfl_down(m_loc, off);
  }
  if (lane == 0){ redbuf[w] = loss_loc; redbuf[4+w] = m_loc; }
  __syncthreads();
  if (t == 0){
    atomicAdd(acc+0, redbuf[0]+redbuf[1]+redbuf[2]+redbuf[3]);
    atomicAdd(acc+1, redbuf[4]+redbuf[5]+redbuf[6]+redbuf[7]);
  }
#undef POLL
#undef PUBLISH
#undef STAGE
}

__global__ void k_fin(const float* __restrict__ acc, float* __restrict__ out){
  if (threadIdx.x == 0){
    out[0] = acc[0];
    out[1] = acc[0]/acc[1];
  }
}

extern "C" void kernel_launch(void* const* d_in, const int* in_sizes, int n_in,
                              void* d_out, int out_size, void* d_ws, size_t ws_size,
                              hipStream_t stream)
{
  const float* X   = (const float*)d_in[0];
  const float* Mm  = (const float*)d_in[1];
  const int*  bidx = (const int*)d_in[2];
  const float* Wi  = (const float*)d_in[4];
  const float* bi  = (const float*)d_in[5];
  const float* Wf  = (const float*)d_in[6];
  const float* bff = (const float*)d_in[7];
  const float* Wo  = (const float*)d_in[8];
  const float* bo  = (const float*)d_in[9];
  const float* Wc  = (const float*)d_in[10];
  const float* bc  = (const float*)d_in[11];
  const float* W1  = (const float*)d_in[12];
  const float* b1  = (const float*)d_in[13];
  const float* W2  = (const float*)d_in[14];
  const float* b2  = (const float*)d_in[15];
  const float* Wp1 = (const float*)d_in[16];
  const float* bp1 = (const float*)d_in[17];
  const float* Wp2 = (const float*)d_in[18];
  const float* bp2 = (const float*)d_in[19];

  char* ws = (char*)d_ws;
  int*    pos = (int*)ws;
  float*  acc = (float*)(ws + 131072);
  int*    flg = (int*)(ws + 196608);
  __half* Hf  = (__half*)(ws + 1048576);
  __half* Tf  = (__half*)(ws + 1572864);
  __half* T2f = (__half*)(ws + 2097152);
  __half* Hf2 = (__half*)(ws + 2621440);
  __half* WF  = (__half*)(ws + 4194304);

  k_init   <<<512, 256, 0, stream>>>(pos, acc, flg, (uint32_t*)Hf);
  k_scatter<<<(Kn*En + 255)/256, 256, 0, stream>>>(bidx, pos);

  k_cvt_frag<<<(262144+255)/256, 256, 0, stream>>>(W1,  WF,          16, 512, 262144);
  k_cvt_frag<<<(262144+255)/256, 256, 0, stream>>>(W2,  WF + 262144, 16, 512, 262144);
  k_cvt_frag<<<(262144+255)/256, 256, 0, stream>>>(Wp1, WF + 524288, 16, 512, 262144);
  k_cvt_frag<<<(65536 +255)/256, 256, 0, stream>>>(Wp2, WF + 786432, 16, 128, 65536);
  k_cvt_frag<<<(327680+255)/256, 256, 0, stream>>>(Wi,  WF + 851968,            20, 512, 327680);
  k_cvt_frag<<<(327680+255)/256, 256, 0, stream>>>(Wf,  WF + 851968 + 327680,   20, 512, 327680);
  k_cvt_frag<<<(327680+255)/256, 256, 0, stream>>>(Wo,  WF + 851968 + 655360,   20, 512, 327680);
  k_cvt_frag<<<(327680+255)/256, 256, 0, stream>>>(Wc,  WF + 851968 + 983040,   20, 512, 327680);

  k_main<<<NBLK, NTH, 0, stream>>>(X, Mm, pos, WF, Hf, Tf, T2f, Hf2,
                                   bi, bff, bo, bc, b1, b2, bp1, bp2, acc, flg);
  k_fin<<<1, 64, 0, stream>>>(acc, (float*)d_out);
}